// Round 3
// baseline (373.074 us; speedup 1.0000x reference)
//
#include <hip/hip_runtime.h>
#include <stdint.h>

#define B_ 8
#define C_ 32
#define N_ 4096
#define KOUT 9
#define RPB 8       // rows (centers) per block; wave w selects row w
#define TPB 512     // 8 waves

// slack coefficients for the f16-dot2 bound:
// |d_exact - d_approx| <= 2*(2^-10 + small)*E, E <= sqrt(si*sj) <= (si+sj)/2
// => needed coef 0.00098*(si+sj); SLC has 1.5x margin. SLA covers fp32 combine
// rounding (~1e-4), f16-denormal flush (~7e-4), accumulation rounding.
#define SLC 0.0015f
#define SLA 0.004f

// workspace layout (bytes): [sq: 128K][xp f16-pairs: 2M][xT f32: 4M]
#define SQ_FLOATS   (B_ * N_)                   // 32768 floats
#define XP_OFF_U32  (SQ_FLOATS)                 // u32 index into ws
#define XT_OFF_F32  (SQ_FLOATS + B_ * (C_/2) * N_)   // 32768 + 524288 = 557056
#define NEED_XP_B   ((size_t)(XT_OFF_F32) * 4)       // 2,228,224
#define NEED_XT_B   (NEED_XP_B + (size_t)B_ * N_ * C_ * 4)  // 6,422,528

typedef unsigned long long u64;
typedef unsigned int u32;
typedef _Float16 h2 __attribute__((ext_vector_type(2)));

#if defined(__has_builtin)
#  if __has_builtin(__builtin_amdgcn_fdot2)
#    define HAVE_FDOT2 1
#  endif
#endif
#ifndef HAVE_FDOT2
#  define HAVE_FDOT2 0
#endif

// f16-pair dot with f32 accumulate. Products of f16 are exact in f32; bound
// in SLC/SLA covers either the fused dot2 or the 2-fma fallback.
__device__ __forceinline__ float dot2acc(u32 a, u32 b, float acc) {
#if HAVE_FDOT2
    return __builtin_amdgcn_fdot2(__builtin_bit_cast(h2, a),
                                  __builtin_bit_cast(h2, b), acc, false);
#else
    h2 ha = __builtin_bit_cast(h2, a), hb = __builtin_bit_cast(h2, b);
    acc = __builtin_fmaf((float)ha.x, (float)hb.x, acc);
    return __builtin_fmaf((float)ha.y, (float)hb.y, acc);
#endif
}

// monotone float->uint mapping: a<b  <=>  fkey(a)<fkey(b)  (pack time only)
__device__ __forceinline__ u32 fkey(float f) {
    u32 u = __float_as_uint(f);
    return u ^ (u32)((((int)u) >> 31) | 0x80000000u);
}

// branchless insert of k into sorted L0<=..<=L5 (keep 6 smallest) — fallback only
__device__ __forceinline__ void ins6(u64 k, u64& L0, u64& L1, u64& L2,
                                     u64& L3, u64& L4, u64& L5) {
    bool lt0 = k < L0, lt1 = k < L1, lt2 = k < L2,
         lt3 = k < L3, lt4 = k < L4, lt5 = k < L5;
    L5 = lt4 ? L4 : (lt5 ? k : L5);
    L4 = lt3 ? L3 : (lt4 ? k : L4);
    L3 = lt2 ? L2 : (lt3 ? k : L3);
    L2 = lt1 ? L1 : (lt2 ? k : L2);
    L1 = lt0 ? L0 : (lt1 ? k : L1);
    L0 = lt0 ? k : L0;
}

// ---------- mode-0 fallback: proven R13 pipeline (sq + exact knn) ----------

__global__ __launch_bounds__(256) void sq_kernel(const float* __restrict__ x,
                                                 float* __restrict__ sq) {
#pragma clang fp contract(off)
    int gid = blockIdx.x * 256 + threadIdx.x;
    int b = gid >> 12, n = gid & (N_ - 1);
    const float* xp = x + (size_t)b * (C_ * N_) + n;
    float w[C_];
#pragma unroll
    for (int c = 0; c < C_; ++c) { float v = xp[(size_t)c * N_]; w[c] = v * v; }
    float r[8];
#pragma unroll
    for (int j = 0; j < 8; ++j) r[j] = w[j];
#pragma unroll
    for (int i = 8; i < 32; i += 8) {
#pragma unroll
        for (int j = 0; j < 8; ++j) r[j] = r[j] + w[i + j];
    }
    sq[gid] = ((r[0] + r[1]) + (r[2] + r[3])) + ((r[4] + r[5]) + (r[6] + r[7]));
}

__global__ __launch_bounds__(TPB, 4) void knn_kernel_old(const float* __restrict__ x,
                                                         const float* __restrict__ sq,
                                                         int* __restrict__ out) {
#pragma clang fp contract(off)
    __shared__ float cenL[C_][RPB];
    __shared__ float mL[RPB][8][64];
    __shared__ u64 bufL[RPB][64];
    __shared__ u32 cntL[RPB];
    __shared__ float tL[RPB];

    const int tid = threadIdx.x;
    const int b = blockIdx.x & 7;
    const int i0 = (blockIdx.x >> 3) * RPB;
    const float* xb = x + (size_t)b * (C_ * N_);
    const float* sqb = sq + b * N_;

    if (tid < RPB * C_) {
        int r = tid & (RPB - 1), c = tid >> 3;
        cenL[c][r] = xb[(size_t)c * N_ + (i0 + r)];
    }
    __syncthreads();

    float acc[RPB][8];
#pragma unroll
    for (int r = 0; r < RPB; ++r)
#pragma unroll
        for (int q = 0; q < 8; ++q) acc[r][q] = 0.0f;

    const int j0 = tid << 2;
#pragma unroll 1
    for (int cc = 0; cc < C_; cc += 4) {
        float4 v0[4], v1[4];
#pragma unroll
        for (int e = 0; e < 4; ++e) {
            const float* xc = xb + (size_t)(cc + e) * N_;
            v0[e] = *(const float4*)(xc + j0);
            v1[e] = *(const float4*)(xc + 2048 + j0);
        }
#pragma unroll
        for (int e = 0; e < 4; ++e) {
            const float* cg = xb + (size_t)(cc + e) * N_ + i0;
            float ce[8];
#pragma unroll
            for (int r = 0; r < RPB; ++r) ce[r] = cg[r];
            float vv[8] = {v0[e].x, v0[e].y, v0[e].z, v0[e].w,
                           v1[e].x, v1[e].y, v1[e].z, v1[e].w};
#pragma unroll
            for (int r = 0; r < RPB; ++r)
#pragma unroll
                for (int q = 0; q < 8; ++q)
                    acc[r][q] = __builtin_fmaf(ce[r], vv[q], acc[r][q]);
        }
    }

    const int wv = tid >> 6, lane = tid & 63;
    float fk[RPB][8];
    {
        float4 s0 = *(const float4*)(sqb + j0);
        float4 s1 = *(const float4*)(sqb + 2048 + j0);
        float sj[8] = {s0.x, s0.y, s0.z, s0.w, s1.x, s1.y, s1.z, s1.w};
#pragma unroll
        for (int r = 0; r < RPB; ++r) {
            float sqi = sqb[i0 + r];
#pragma unroll
            for (int q = 0; q < 8; ++q)
                fk[r][q] = __builtin_fmaf(-2.0f, acc[r][q], sqi) + sj[q];
        }
    }

    float minr[RPB];
#pragma unroll
    for (int r = 0; r < RPB; ++r) {
        float mn = fk[r][0];
#pragma unroll
        for (int q = 1; q < 8; ++q) mn = fminf(mn, fk[r][q]);
        minr[r] = mn;
        mL[r][wv][lane] = mn;
    }
    if (tid < RPB) cntL[tid] = 0;
    __syncthreads();

    {
        float mn = mL[wv][0][lane];
#pragma unroll
        for (int s = 1; s < 8; ++s) mn = fminf(mn, mL[wv][s][lane]);
        float v32 = mn;
#pragma unroll
        for (int k = 2; k <= 64; k <<= 1) {
#pragma unroll
            for (int j = k >> 1; j >= 1; j >>= 1) {
                float pv = __shfl_xor(v32, j);
                bool keepMin = (((lane & j) == 0) == ((lane & k) == 0));
                float lo = v32 < pv ? v32 : pv;
                float hi = v32 < pv ? pv : v32;
                v32 = keepMin ? lo : hi;
            }
        }
        if (lane == 17) tL[wv] = v32;
    }
    __syncthreads();

    {
#pragma unroll
        for (int r = 0; r < RPB; ++r) {
            float Tr = tL[r];
            if (minr[r] <= Tr) {
#pragma unroll
                for (int q = 0; q < 8; ++q) {
                    if (fk[r][q] <= Tr) {
                        int jq = ((q >> 2) << 11) + j0 + (q & 3);
                        u32 s = atomicAdd(&cntL[r], 1u);
                        if (s < 64) bufL[r][s] = ((u64)fkey(fk[r][q]) << 32) | (u32)jq;
                    }
                }
            }
        }
    }
    __syncthreads();

    {
        const int w = wv;
        const u32 cnt = cntL[w];
        const int row = b * N_ + i0 + w;
        if (cnt <= 64) {
            u64 myc = (lane < (int)cnt) ? bufL[w][lane] : ~0ull;
            u32 rank = 0;
            for (u32 m = 0; m < cnt; ++m) {
                u64 o = bufL[w][m];
                rank += (o < myc) ? 1u : 0u;
            }
            if (lane < (int)cnt && rank <= 16 && (rank & 1) == 0)
                out[row * KOUT + (rank >> 1)] = (int)((u32)myc & (N_ - 1));
            if (lane < KOUT)
                out[B_ * N_ * KOUT + row * KOUT + lane] = i0 + w;
        } else {
            const float sqw = sqb[i0 + w];
            u64 L0 = ~0ull, L1 = ~0ull, L2 = ~0ull, L3 = ~0ull, L4 = ~0ull, L5 = ~0ull;
#pragma unroll 1
            for (int m = 0; m < 64; ++m) {
                int j = lane + (m << 6);
                float a = 0.0f;
#pragma unroll 1
                for (int c = 0; c < C_; ++c)
                    a = __builtin_fmaf(cenL[c][w], xb[(size_t)c * N_ + j], a);
                float d = __builtin_fmaf(-2.0f, a, sqw) + sqb[j];
                ins6(((u64)fkey(d) << 32) | (u32)j, L0, L1, L2, L3, L4, L5);
            }
            u64 lastPop = 0;
            u32 myw = 0;
#pragma unroll 1
            for (int r = 0; r < KOUT; ++r) {
                u64 a0 = L0, a1 = L1;
#pragma unroll
                for (int off = 32; off >= 1; off >>= 1) {
                    u64 b0 = __shfl_xor(a0, off);
                    u64 b1 = __shfl_xor(a1, off);
                    u64 lo = (a0 < b0) ? a0 : b0;
                    u64 hi = (a0 < b0) ? b0 : a0;
                    u64 m1 = (a1 < b1) ? a1 : b1;
                    a0 = lo;
                    a1 = (hi < m1) ? hi : m1;
                }
                if (lane == r) myw = (u32)a0;
                bool own0 = ((u32)a0 & 63) == (u32)lane;
                bool own1 = ((u32)a1 & 63) == (u32)lane;
                if (own0) { lastPop = a0; L0 = L1; L1 = L2; L2 = L3; L3 = L4; L4 = L5; L5 = ~0ull; }
                if (own1) { lastPop = a1; L0 = L1; L1 = L2; L2 = L3; L3 = L4; L4 = L5; L5 = ~0ull; }
                if ((own0 || own1) && L1 == ~0ull && r < KOUT - 1) {
                    L0 = L1 = L2 = L3 = L4 = L5 = ~0ull;
#pragma unroll 1
                    for (int m = 0; m < 64; ++m) {
                        int j = lane + (m << 6);
                        float a = 0.0f;
#pragma unroll 1
                        for (int c = 0; c < C_; ++c)
                            a = __builtin_fmaf(cenL[c][w], xb[(size_t)c * N_ + j], a);
                        float d = __builtin_fmaf(-2.0f, a, sqw) + sqb[j];
                        u64 kk = ((u64)fkey(d) << 32) | (u32)j;
                        if (kk > lastPop) ins6(kk, L0, L1, L2, L3, L4, L5);
                    }
                }
            }
            if (lane < KOUT) {
                int o = row * KOUT + lane;
                out[o] = (int)(myw & (N_ - 1));
                out[B_ * N_ * KOUT + o] = i0 + w;
            }
        }
    }
}

// ---------- mode-1/2: prep (sq + f16 channel-pairs + optional f32 transpose) ----------

__global__ __launch_bounds__(256) void prep_kernel(const float* __restrict__ x,
                                                   float* __restrict__ ws, int useXT) {
#pragma clang fp contract(off)
    int gid = blockIdx.x * 256 + threadIdx.x;
    int b = gid >> 12, n = gid & (N_ - 1);
    const float* xpd = x + (size_t)b * (C_ * N_) + n;
    float v[C_];
#pragma unroll
    for (int c = 0; c < C_; ++c) v[c] = xpd[(size_t)c * N_];
    // sq: proven 8-acc numpy pattern (bit-exact, R1)
    float w[C_];
#pragma unroll
    for (int c = 0; c < C_; ++c) w[c] = v[c] * v[c];
    float r[8];
#pragma unroll
    for (int j = 0; j < 8; ++j) r[j] = w[j];
#pragma unroll
    for (int i = 8; i < 32; i += 8) {
#pragma unroll
        for (int j = 0; j < 8; ++j) r[j] = r[j] + w[i + j];
    }
    ws[gid] = ((r[0] + r[1]) + (r[2] + r[3])) + ((r[4] + r[5]) + (r[6] + r[7]));
    // xp: f16 channel-pair packed [b][c/2][n] (RNE converts)
    u32* xp = (u32*)ws + XP_OFF_U32;
#pragma unroll
    for (int p = 0; p < C_ / 2; ++p) {
        h2 hh;
        hh.x = (_Float16)v[2 * p];
        hh.y = (_Float16)v[2 * p + 1];
        xp[((size_t)b * (C_ / 2) + p) * N_ + n] = __builtin_bit_cast(u32, hh);
    }
    // xT: f32 transpose [b][n][c] for coalesced exact-candidate gather
    if (useXT) {
        float* dst = ws + XT_OFF_F32 + ((size_t)b * N_ + n) * C_;
#pragma unroll
        for (int c = 0; c < C_; ++c) dst[c] = v[c];
    }
}

// ---------- mode-1/2: dot2-prefilter knn with exact candidate verification ----------

__global__ __launch_bounds__(TPB, 4) void knn_kernel_v2(const float* __restrict__ x,
                                                        const float* __restrict__ ws,
                                                        int* __restrict__ out, int useXT) {
#pragma clang fp contract(off)
    __shared__ float cenL[C_][RPB];      // exact f32 centers (candidate + fallback)
    __shared__ float mL[RPB][8][64];     // per-(row, src-wave, lane) min UPPER bound
    __shared__ u64 bufL[RPB][64];        // candidate j's, then exact keys
    __shared__ u32 cntL[RPB];
    __shared__ float tL[RPB];

    const int tid = threadIdx.x;
    const int b = blockIdx.x & 7;               // XCD-batch affinity (proven R2)
    const int i0 = (blockIdx.x >> 3) * RPB;
    const float* xb = x + (size_t)b * (C_ * N_);
    const float* sqb = ws + b * N_;
    const u32* xpb = (const u32*)ws + XP_OFF_U32 + (size_t)b * (C_ / 2) * N_;
    const float* xTb = ws + XT_OFF_F32 + (size_t)b * N_ * C_;

    if (tid < RPB * C_) {
        int rr = tid & (RPB - 1), c = tid >> 3;
        cenL[c][rr] = xb[(size_t)c * N_ + (i0 + rr)];
    }
    __syncthreads();

    // ---- phase 1: f16 dot2 inner products (2 MAC/instr). Thread t owns
    // j(q) = ((q>>2)<<11) + 4t + (q&3), same as R13. 16 channel-pairs.
    // Accumulation order is irrelevant here — result is only used via bounds.
    float acc[RPB][8];
#pragma unroll
    for (int rr = 0; rr < RPB; ++rr)
#pragma unroll
        for (int q = 0; q < 8; ++q) acc[rr][q] = 0.0f;

    const int j0 = tid << 2;
#pragma unroll 1
    for (int pp = 0; pp < C_ / 2; pp += 4) {
        uint4 v0[4], v1[4];              // 8 b128 loads in flight (R13 pattern)
#pragma unroll
        for (int e = 0; e < 4; ++e) {
            const u32* xc = xpb + (size_t)(pp + e) * N_;
            v0[e] = *(const uint4*)(xc + j0);
            v1[e] = *(const uint4*)(xc + 2048 + j0);
        }
#pragma unroll
        for (int e = 0; e < 4; ++e) {
            const u32* cgp = xpb + (size_t)(pp + e) * N_ + i0;  // uniform address
            u32 cu[RPB];
#pragma unroll
            for (int rr = 0; rr < RPB; ++rr) cu[rr] = cgp[rr];  // scalar loads
            u32 ju[8] = {v0[e].x, v0[e].y, v0[e].z, v0[e].w,
                         v1[e].x, v1[e].y, v1[e].z, v1[e].w};
#pragma unroll
            for (int rr = 0; rr < RPB; ++rr)
#pragma unroll
                for (int q = 0; q < 8; ++q)
                    acc[rr][q] = dot2acc(cu[rr], ju[q], acc[rr][q]);
        }
    }

    // ---- epilogue: UPPER bounds. d~ = fmaf(-2,acc,si)+sj; sl = SLC*(si+sj)+SLA;
    // up = d~ + sl  (stored over acc). lower = up - 2*sl tested in scan.
    const int wv = tid >> 6, lane = tid & 63;
    float sj[8], sqi8[RPB];
    {
        float4 s0 = *(const float4*)(sqb + j0);
        float4 s1 = *(const float4*)(sqb + 2048 + j0);
        sj[0] = s0.x; sj[1] = s0.y; sj[2] = s0.z; sj[3] = s0.w;
        sj[4] = s1.x; sj[5] = s1.y; sj[6] = s1.z; sj[7] = s1.w;
    }
    float sjmx = sj[0];
#pragma unroll
    for (int q = 1; q < 8; ++q) sjmx = fmaxf(sjmx, sj[q]);
#pragma unroll
    for (int rr = 0; rr < RPB; ++rr) {
        float sqi = sqb[i0 + rr];
        sqi8[rr] = sqi;
#pragma unroll
        for (int q = 0; q < 8; ++q) {
            float dt = __builtin_fmaf(-2.0f, acc[rr][q], sqi) + sj[q];
            float sl = __builtin_fmaf(sqi + sj[q], SLC, SLA);
            acc[rr][q] = dt + sl;        // upper bound
        }
    }

    // per-thread per-row min upper -> mL
    float minr[RPB];
#pragma unroll
    for (int rr = 0; rr < RPB; ++rr) {
        float mn = acc[rr][0];
#pragma unroll
        for (int q = 1; q < 8; ++q) mn = fminf(mn, acc[rr][q]);
        minr[rr] = mn;
        mL[rr][wv][lane] = mn;
    }
    if (tid < RPB) cntL[tid] = 0;
    __syncthreads();

    // ---- T = 18th-smallest partition min of UPPER bounds. >=18 distinct j
    // have up <= T  =>  T >= 18th exact distance  =>  scan on lower bounds
    // admits every true top-18 element. (R9/R10 partition guarantee intact.)
    {
        float mn = mL[wv][0][lane];
#pragma unroll
        for (int s = 1; s < 8; ++s) mn = fminf(mn, mL[wv][s][lane]);
        float v32 = mn;
#pragma unroll
        for (int k = 2; k <= 64; k <<= 1) {
#pragma unroll
            for (int j = k >> 1; j >= 1; j >>= 1) {
                float pv = __shfl_xor(v32, j);
                bool keepMin = (((lane & j) == 0) == ((lane & k) == 0));
                float lo = v32 < pv ? v32 : pv;
                float hi = v32 < pv ? pv : v32;
                v32 = keepMin ? lo : hi;
            }
        }
        if (lane == 17) tL[wv] = v32;    // sorted[17] lives in lane 17
    }
    __syncthreads();

    // ---- scan B: admit j if lower = up - 2*sl <= T. Store j only; exact
    // keys are computed in parallel in the rank phase.
    {
#pragma unroll
        for (int rr = 0; rr < RPB; ++rr) {
            float Tr = tL[rr];
            float slmax = __builtin_fmaf(sqi8[rr] + sjmx, SLC, SLA);
            if (minr[rr] - 2.0f * slmax <= Tr) {   // conservative row skip (~96%)
#pragma unroll
                for (int q = 0; q < 8; ++q) {
                    float sl = __builtin_fmaf(sqi8[rr] + sj[q], SLC, SLA);
                    if (acc[rr][q] <= __builtin_fmaf(2.0f, sl, Tr)) {
                        int jq = ((q >> 2) << 11) + j0 + (q & 3);
                        u32 s = atomicAdd(&cntL[rr], 1u);
                        if (s < 64) bufL[rr][s] = (u64)(u32)jq;
                    }
                }
            }
        }
    }
    __syncthreads();

    // ---- wave wv: exact-verify candidates in parallel (lane = candidate),
    // then rank-by-counting with exact keys.
    {
        const int w = wv;
        const u32 cnt = cntL[w];
        const int row = b * N_ + i0 + w;
        if (cnt <= 64) {
            u64 myc = ~0ull;
            if (lane < (int)cnt) {
                int jq = (int)(u32)bufL[w][lane];
                // exact chain: c ascending, fmaf — bit-identical to reference
                float a = 0.0f;
                if (useXT) {
                    const float* xj = xTb + (size_t)jq * C_;   // 128B contiguous
#pragma unroll
                    for (int c = 0; c < C_; ++c)
                        a = __builtin_fmaf(cenL[c][w], xj[c], a);
                } else {
#pragma unroll
                    for (int c = 0; c < C_; ++c)
                        a = __builtin_fmaf(cenL[c][w], xb[(size_t)c * N_ + jq], a);
                }
                float d = __builtin_fmaf(-2.0f, a, sqi8[w]) + sqb[jq];
                myc = ((u64)fkey(d) << 32) | (u32)jq;
                bufL[w][lane] = myc;     // same-wave LDS: in-order, no barrier
            }
            u32 rank = 0;
            for (u32 m = 0; m < cnt; ++m) {
                u64 o = bufL[w][m];          // same-address broadcast read
                rank += (o < myc) ? 1u : 0u;
            }
            // dilated output = sorted positions 0,2,...,16 -> slot rank/2
            if (lane < (int)cnt && rank <= 16 && (rank & 1) == 0)
                out[row * KOUT + (rank >> 1)] = (int)((u32)myc & (N_ - 1));
            if (lane < KOUT)
                out[B_ * N_ * KOUT + row * KOUT + lane] = i0 + w;
        } else {
            // ---- fallback (astronomically rare): exact scan + pop-2, proven R7
            const float sqw = sqb[i0 + w];
            u64 L0 = ~0ull, L1 = ~0ull, L2 = ~0ull, L3 = ~0ull, L4 = ~0ull, L5 = ~0ull;
#pragma unroll 1
            for (int m = 0; m < 64; ++m) {
                int j = lane + (m << 6);
                float a = 0.0f;
#pragma unroll 1
                for (int c = 0; c < C_; ++c)
                    a = __builtin_fmaf(cenL[c][w], xb[(size_t)c * N_ + j], a);
                float d = __builtin_fmaf(-2.0f, a, sqw) + sqb[j];
                ins6(((u64)fkey(d) << 32) | (u32)j, L0, L1, L2, L3, L4, L5);
            }
            u64 lastPop = 0;
            u32 myw = 0;
#pragma unroll 1
            for (int r = 0; r < KOUT; ++r) {
                u64 a0 = L0, a1 = L1;
#pragma unroll
                for (int off = 32; off >= 1; off >>= 1) {
                    u64 b0 = __shfl_xor(a0, off);
                    u64 b1 = __shfl_xor(a1, off);
                    u64 lo = (a0 < b0) ? a0 : b0;
                    u64 hi = (a0 < b0) ? b0 : a0;
                    u64 m1 = (a1 < b1) ? a1 : b1;
                    a0 = lo;
                    a1 = (hi < m1) ? hi : m1;
                }
                if (lane == r) myw = (u32)a0;
                bool own0 = ((u32)a0 & 63) == (u32)lane;
                bool own1 = ((u32)a1 & 63) == (u32)lane;
                if (own0) { lastPop = a0; L0 = L1; L1 = L2; L2 = L3; L3 = L4; L4 = L5; L5 = ~0ull; }
                if (own1) { lastPop = a1; L0 = L1; L1 = L2; L2 = L3; L3 = L4; L4 = L5; L5 = ~0ull; }
                if ((own0 || own1) && L1 == ~0ull && r < KOUT - 1) {
                    L0 = L1 = L2 = L3 = L4 = L5 = ~0ull;
#pragma unroll 1
                    for (int m = 0; m < 64; ++m) {
                        int j = lane + (m << 6);
                        float a = 0.0f;
#pragma unroll 1
                        for (int c = 0; c < C_; ++c)
                            a = __builtin_fmaf(cenL[c][w], xb[(size_t)c * N_ + j], a);
                        float d = __builtin_fmaf(-2.0f, a, sqw) + sqb[j];
                        u64 kk = ((u64)fkey(d) << 32) | (u32)j;
                        if (kk > lastPop) ins6(kk, L0, L1, L2, L3, L4, L5);
                    }
                }
            }
            if (lane < KOUT) {
                int o = row * KOUT + lane;
                out[o] = (int)(myw & (N_ - 1));
                out[B_ * N_ * KOUT + o] = i0 + w;
            }
        }
    }
}

extern "C" void kernel_launch(void* const* d_in, const int* in_sizes, int n_in,
                              void* d_out, int out_size, void* d_ws, size_t ws_size,
                              hipStream_t stream) {
    const float* x = (const float*)d_in[0];
    float* ws = (float*)d_ws;
    int* out = (int*)d_out;

    if (ws_size >= NEED_XP_B) {
        int useXT = (ws_size >= NEED_XT_B) ? 1 : 0;
        hipLaunchKernelGGL(prep_kernel, dim3(B_ * N_ / 256), dim3(256), 0, stream,
                           x, ws, useXT);
        hipLaunchKernelGGL(knn_kernel_v2, dim3(B_ * N_ / RPB), dim3(TPB), 0, stream,
                           x, ws, out, useXT);
    } else {
        hipLaunchKernelGGL(sq_kernel, dim3(B_ * N_ / 256), dim3(256), 0, stream, x, ws);
        hipLaunchKernelGGL(knn_kernel_old, dim3(B_ * N_ / RPB), dim3(TPB), 0, stream,
                           x, ws, out);
    }
}

// Round 5
// 172.996 us; speedup vs baseline: 2.1566x; 2.1566x over previous
//
#include <hip/hip_runtime.h>
#include <stdint.h>

#define B_ 8
#define C_ 32
#define N_ 4096
#define KOUT 9

// mode-0 legacy (tiny workspace) params
#define RPB 8
#define TPB 512

// mode-1 (MFMA prefilter) params
#define RPB2 16     // rows per block; wave w verifies rows 2w, 2w+1
#define TPB2 512    // 8 waves; wave w scans j in [512w, 512w+512)

// bf16 bound slack: |d_exact - d_mfma| <= (2u+u^2)*(si+sj), u=2^-8 -> 0.00787
// SLC2 = 1.5x margin; SLA2 covers f32 combine rounding + denormal flush.
#define SLC2 0.012f
#define SLA2 0.004f

// ws layout (float units): [sq: B*N][xbf u32: B*N*16][xT f32: B*N*32]
#define SQ_FLOATS   (B_ * N_)
#define XP_OFF_U32  (SQ_FLOATS)
#define XT_OFF_F32  (SQ_FLOATS + B_ * 16 * N_)
#define NEED_XT_B   ((size_t)(XT_OFF_F32 + B_ * N_ * C_) * 4)   // 6,422,528

typedef unsigned long long u64;
typedef unsigned int u32;
typedef __attribute__((ext_vector_type(8))) short short8;   // 8 bf16 (4 VGPRs)
typedef __attribute__((ext_vector_type(4))) float f32x4;

// monotone float->uint mapping and inverse: a<b <=> fkey(a)<fkey(b)
__device__ __forceinline__ u32 fkey(float f) {
    u32 u = __float_as_uint(f);
    return u ^ (u32)((((int)u) >> 31) | 0x80000000u);
}
__device__ __forceinline__ float unfkey(u32 k) {
    u32 u = (k & 0x80000000u) ? (k ^ 0x80000000u) : ~k;
    return __uint_as_float(u);
}

// f32 -> bf16 RNE (no NaN/Inf in data)
__device__ __forceinline__ u32 rne_bf16(float f) {
    u32 u = __float_as_uint(f);
    return (u + 0x7fffu + ((u >> 16) & 1u)) >> 16;
}

// branchless insert keep-6-smallest — exact fallback only
__device__ __forceinline__ void ins6(u64 k, u64& L0, u64& L1, u64& L2,
                                     u64& L3, u64& L4, u64& L5) {
    bool lt0 = k < L0, lt1 = k < L1, lt2 = k < L2,
         lt3 = k < L3, lt4 = k < L4, lt5 = k < L5;
    L5 = lt4 ? L4 : (lt5 ? k : L5);
    L4 = lt3 ? L3 : (lt4 ? k : L4);
    L3 = lt2 ? L2 : (lt3 ? k : L3);
    L2 = lt1 ? L1 : (lt2 ? k : L2);
    L1 = lt0 ? L0 : (lt1 ? k : L1);
    L0 = lt0 ? k : L0;
}

// ---------------- mode-0: proven R13 pipeline (unchanged) ----------------

__global__ __launch_bounds__(256) void sq_kernel(const float* __restrict__ x,
                                                 float* __restrict__ sq) {
#pragma clang fp contract(off)
    int gid = blockIdx.x * 256 + threadIdx.x;
    int b = gid >> 12, n = gid & (N_ - 1);
    const float* xp = x + (size_t)b * (C_ * N_) + n;
    float w[C_];
#pragma unroll
    for (int c = 0; c < C_; ++c) { float v = xp[(size_t)c * N_]; w[c] = v * v; }
    float r[8];
#pragma unroll
    for (int j = 0; j < 8; ++j) r[j] = w[j];
#pragma unroll
    for (int i = 8; i < 32; i += 8) {
#pragma unroll
        for (int j = 0; j < 8; ++j) r[j] = r[j] + w[i + j];
    }
    sq[gid] = ((r[0] + r[1]) + (r[2] + r[3])) + ((r[4] + r[5]) + (r[6] + r[7]));
}

__global__ __launch_bounds__(TPB, 4) void knn_kernel_old(const float* __restrict__ x,
                                                         const float* __restrict__ sq,
                                                         int* __restrict__ out) {
#pragma clang fp contract(off)
    __shared__ float cenL[C_][RPB];
    __shared__ float mL[RPB][8][64];
    __shared__ u64 bufL[RPB][64];
    __shared__ u32 cntL[RPB];
    __shared__ float tL[RPB];

    const int tid = threadIdx.x;
    const int b = blockIdx.x & 7;
    const int i0 = (blockIdx.x >> 3) * RPB;
    const float* xb = x + (size_t)b * (C_ * N_);
    const float* sqb = sq + b * N_;

    if (tid < RPB * C_) {
        int r = tid & (RPB - 1), c = tid >> 3;
        cenL[c][r] = xb[(size_t)c * N_ + (i0 + r)];
    }
    __syncthreads();

    float acc[RPB][8];
#pragma unroll
    for (int r = 0; r < RPB; ++r)
#pragma unroll
        for (int q = 0; q < 8; ++q) acc[r][q] = 0.0f;

    const int j0 = tid << 2;
#pragma unroll 1
    for (int cc = 0; cc < C_; cc += 4) {
        float4 v0[4], v1[4];
#pragma unroll
        for (int e = 0; e < 4; ++e) {
            const float* xc = xb + (size_t)(cc + e) * N_;
            v0[e] = *(const float4*)(xc + j0);
            v1[e] = *(const float4*)(xc + 2048 + j0);
        }
#pragma unroll
        for (int e = 0; e < 4; ++e) {
            const float* cg = xb + (size_t)(cc + e) * N_ + i0;
            float ce[8];
#pragma unroll
            for (int r = 0; r < RPB; ++r) ce[r] = cg[r];
            float vv[8] = {v0[e].x, v0[e].y, v0[e].z, v0[e].w,
                           v1[e].x, v1[e].y, v1[e].z, v1[e].w};
#pragma unroll
            for (int r = 0; r < RPB; ++r)
#pragma unroll
                for (int q = 0; q < 8; ++q)
                    acc[r][q] = __builtin_fmaf(ce[r], vv[q], acc[r][q]);
        }
    }

    const int wv = tid >> 6, lane = tid & 63;
    float fk[RPB][8];
    {
        float4 s0 = *(const float4*)(sqb + j0);
        float4 s1 = *(const float4*)(sqb + 2048 + j0);
        float sj[8] = {s0.x, s0.y, s0.z, s0.w, s1.x, s1.y, s1.z, s1.w};
#pragma unroll
        for (int r = 0; r < RPB; ++r) {
            float sqi = sqb[i0 + r];
#pragma unroll
            for (int q = 0; q < 8; ++q)
                fk[r][q] = __builtin_fmaf(-2.0f, acc[r][q], sqi) + sj[q];
        }
    }

    float minr[RPB];
#pragma unroll
    for (int r = 0; r < RPB; ++r) {
        float mn = fk[r][0];
#pragma unroll
        for (int q = 1; q < 8; ++q) mn = fminf(mn, fk[r][q]);
        minr[r] = mn;
        mL[r][wv][lane] = mn;
    }
    if (tid < RPB) cntL[tid] = 0;
    __syncthreads();

    {
        float mn = mL[wv][0][lane];
#pragma unroll
        for (int s = 1; s < 8; ++s) mn = fminf(mn, mL[wv][s][lane]);
        float v32 = mn;
#pragma unroll
        for (int k = 2; k <= 64; k <<= 1) {
#pragma unroll
            for (int j = k >> 1; j >= 1; j >>= 1) {
                float pv = __shfl_xor(v32, j);
                bool keepMin = (((lane & j) == 0) == ((lane & k) == 0));
                float lo = v32 < pv ? v32 : pv;
                float hi = v32 < pv ? pv : v32;
                v32 = keepMin ? lo : hi;
            }
        }
        if (lane == 17) tL[wv] = v32;
    }
    __syncthreads();

    {
#pragma unroll
        for (int r = 0; r < RPB; ++r) {
            float Tr = tL[r];
            if (minr[r] <= Tr) {
#pragma unroll
                for (int q = 0; q < 8; ++q) {
                    if (fk[r][q] <= Tr) {
                        int jq = ((q >> 2) << 11) + j0 + (q & 3);
                        u32 s = atomicAdd(&cntL[r], 1u);
                        if (s < 64) bufL[r][s] = ((u64)fkey(fk[r][q]) << 32) | (u32)jq;
                    }
                }
            }
        }
    }
    __syncthreads();

    {
        const int w = wv;
        const u32 cnt = cntL[w];
        const int row = b * N_ + i0 + w;
        if (cnt <= 64) {
            u64 myc = (lane < (int)cnt) ? bufL[w][lane] : ~0ull;
            u32 rank = 0;
            for (u32 m = 0; m < cnt; ++m) {
                u64 o = bufL[w][m];
                rank += (o < myc) ? 1u : 0u;
            }
            if (lane < (int)cnt && rank <= 16 && (rank & 1) == 0)
                out[row * KOUT + (rank >> 1)] = (int)((u32)myc & (N_ - 1));
            if (lane < KOUT)
                out[B_ * N_ * KOUT + row * KOUT + lane] = i0 + w;
        } else {
            const float sqw = sqb[i0 + w];
            u64 L0 = ~0ull, L1 = ~0ull, L2 = ~0ull, L3 = ~0ull, L4 = ~0ull, L5 = ~0ull;
#pragma unroll 1
            for (int m = 0; m < 64; ++m) {
                int j = lane + (m << 6);
                float a = 0.0f;
#pragma unroll 1
                for (int c = 0; c < C_; ++c)
                    a = __builtin_fmaf(cenL[c][w], xb[(size_t)c * N_ + j], a);
                float d = __builtin_fmaf(-2.0f, a, sqw) + sqb[j];
                ins6(((u64)fkey(d) << 32) | (u32)j, L0, L1, L2, L3, L4, L5);
            }
            u64 lastPop = 0;
            u32 myw = 0;
#pragma unroll 1
            for (int r = 0; r < KOUT; ++r) {
                u64 a0 = L0, a1 = L1;
#pragma unroll
                for (int off = 32; off >= 1; off >>= 1) {
                    u64 b0 = __shfl_xor(a0, off);
                    u64 b1 = __shfl_xor(a1, off);
                    u64 lo = (a0 < b0) ? a0 : b0;
                    u64 hi = (a0 < b0) ? b0 : a0;
                    u64 m1 = (a1 < b1) ? a1 : b1;
                    a0 = lo;
                    a1 = (hi < m1) ? hi : m1;
                }
                if (lane == r) myw = (u32)a0;
                bool own0 = ((u32)a0 & 63) == (u32)lane;
                bool own1 = ((u32)a1 & 63) == (u32)lane;
                if (own0) { lastPop = a0; L0 = L1; L1 = L2; L2 = L3; L3 = L4; L4 = L5; L5 = ~0ull; }
                if (own1) { lastPop = a1; L0 = L1; L1 = L2; L2 = L3; L3 = L4; L4 = L5; L5 = ~0ull; }
                if ((own0 || own1) && L1 == ~0ull && r < KOUT - 1) {
                    L0 = L1 = L2 = L3 = L4 = L5 = ~0ull;
#pragma unroll 1
                    for (int m = 0; m < 64; ++m) {
                        int j = lane + (m << 6);
                        float a = 0.0f;
#pragma unroll 1
                        for (int c = 0; c < C_; ++c)
                            a = __builtin_fmaf(cenL[c][w], xb[(size_t)c * N_ + j], a);
                        float d = __builtin_fmaf(-2.0f, a, sqw) + sqb[j];
                        u64 kk = ((u64)fkey(d) << 32) | (u32)j;
                        if (kk > lastPop) ins6(kk, L0, L1, L2, L3, L4, L5);
                    }
                }
            }
            if (lane < KOUT) {
                int o = row * KOUT + lane;
                out[o] = (int)(myw & (N_ - 1));
                out[B_ * N_ * KOUT + o] = i0 + w;
            }
        }
    }
}

// ---------------- mode-1 prep: sq (exact) + bf16 [n][c] + f32 transpose ----------------

__global__ __launch_bounds__(256) void prep2_kernel(const float* __restrict__ x,
                                                    float* __restrict__ ws) {
#pragma clang fp contract(off)
    int gid = blockIdx.x * 256 + threadIdx.x;
    int b = gid >> 12, n = gid & (N_ - 1);
    const float* xp = x + (size_t)b * (C_ * N_) + n;
    float v[C_];
#pragma unroll
    for (int c = 0; c < C_; ++c) v[c] = xp[(size_t)c * N_];
    // sq: proven 8-acc numpy pattern (bit-exact)
    float w[C_];
#pragma unroll
    for (int c = 0; c < C_; ++c) w[c] = v[c] * v[c];
    float r[8];
#pragma unroll
    for (int j = 0; j < 8; ++j) r[j] = w[j];
#pragma unroll
    for (int i = 8; i < 32; i += 8) {
#pragma unroll
        for (int j = 0; j < 8; ++j) r[j] = r[j] + w[i + j];
    }
    ws[gid] = ((r[0] + r[1]) + (r[2] + r[3])) + ((r[4] + r[5]) + (r[6] + r[7]));
    // xbf[n][c]: 32 bf16 = 16 u32, c ascending (low half = even c)
    u32 pk[16];
#pragma unroll
    for (int p = 0; p < 16; ++p)
        pk[p] = rne_bf16(v[2 * p]) | (rne_bf16(v[2 * p + 1]) << 16);
    u32* xbf = (u32*)ws + XP_OFF_U32 + (size_t)gid * 16;
#pragma unroll
    for (int p = 0; p < 4; ++p)
        *(uint4*)(xbf + 4 * p) = make_uint4(pk[4 * p], pk[4 * p + 1], pk[4 * p + 2], pk[4 * p + 3]);
    // xT[n][c] f32: exact-verify gather source (128 B contiguous per point)
    float* xT = ws + XT_OFF_F32 + (size_t)gid * 32;
#pragma unroll
    for (int p = 0; p < 8; ++p)
        *(float4*)(xT + 4 * p) = make_float4(v[4 * p], v[4 * p + 1], v[4 * p + 2], v[4 * p + 3]);
}

// ---------------- mode-1 knn: MFMA prefilter + proven exact verify ----------------

__global__ __launch_bounds__(TPB2, 4) void knn_kernel_v3(const float* __restrict__ x,
                                                         const float* __restrict__ ws,
                                                         int* __restrict__ out) {
#pragma clang fp contract(off)
    __shared__ float cenL[C_][RPB2];     // 2 KB exact centers (verify + fallback)
    __shared__ float mL[RPB2][64];       // 4 KB per-(row, partition) min upper bound
    __shared__ u64 bufL[RPB2][64];       // 8 KB candidate buffers
    __shared__ u32 cntL[RPB2];
    __shared__ float tL[RPB2];

    const int tid = threadIdx.x;
    const int b = blockIdx.x & 7;               // XCD-batch affinity (proven R2)
    const int i0 = (blockIdx.x >> 3) * RPB2;
    const float* xb = x + (size_t)b * (C_ * N_);
    const float* sqb = ws + b * N_;
    const u32* xbfU = (const u32*)ws + XP_OFF_U32 + (size_t)b * N_ * 16;
    const float* xTb = ws + XT_OFF_F32 + (size_t)b * N_ * 32;

    { int r = tid & 15, c = tid >> 4; cenL[c][r] = xb[(size_t)c * N_ + (i0 + r)]; }
    if (tid < RPB2) cntL[tid] = 0;
    __syncthreads();

    const int w = tid >> 6, l = tid & 63;
    const int col = l & 15, grp = l >> 4;

    // A-frag: lane holds A[row=col][k=8*grp..+7] = xbf[i0+col][8grp..]; B mirrors
    // with n=j. Identical addressing for A and B => any within-frag k-relabel
    // cancels in the contraction. C layout: col=l&15, row=4*grp+reg (m89).
    uint4 au = *(const uint4*)(xbfU + (size_t)(i0 + col) * 16 + grp * 4);
    const short8 afrag = __builtin_bit_cast(short8, au);

    float si4[4];
#pragma unroll
    for (int q = 0; q < 4; ++q) si4[q] = sqb[i0 + grp * 4 + q];

    const int jw = w << 9;                      // wave's j-span base

    // ---- pass 1: per-(row, partition) minima of UPPER bounds.
    // Partition = (wave, col-pair): 64 j's, 64 disjoint partitions covering N.
    float tmin[4] = {3.4e38f, 3.4e38f, 3.4e38f, 3.4e38f};
#pragma unroll 4
    for (int t = 0; t < 32; ++t) {
        const int jb = jw + (t << 4);
        uint4 bu = *(const uint4*)(xbfU + (size_t)(jb + col) * 16 + grp * 4);
        f32x4 c0 = {0.0f, 0.0f, 0.0f, 0.0f};
        c0 = __builtin_amdgcn_mfma_f32_16x16x32_bf16(
                 afrag, __builtin_bit_cast(short8, bu), c0, 0, 0, 0);
        const float sjv = sqb[jb + col];
#pragma unroll
        for (int q = 0; q < 4; ++q) {
            float dt = __builtin_fmaf(-2.0f, c0[q], si4[q]) + sjv;
            float up = dt + __builtin_fmaf(si4[q] + sjv, SLC2, SLA2);
            tmin[q] = fminf(tmin[q], up);
        }
    }
#pragma unroll
    for (int q = 0; q < 4; ++q) tmin[q] = fminf(tmin[q], __shfl_xor(tmin[q], 1));
    if (!(l & 1)) {
        const int cp = col >> 1;
#pragma unroll
        for (int q = 0; q < 4; ++q) mL[grp * 4 + q][(w << 3) + cp] = tmin[q];
    }
    __syncthreads();

    // ---- T[row] = 18th-smallest partition min of upper bounds => >=18 j with
    // up <= T => T >= 18th exact distance => lower-bound scan admits all true
    // top-18 (v2-proven argument). Wave w handles rows 2w, 2w+1.
#pragma unroll
    for (int sub = 0; sub < 2; ++sub) {
        const int rr = 2 * w + sub;
        float v32 = mL[rr][l];
#pragma unroll
        for (int k = 2; k <= 64; k <<= 1) {
#pragma unroll
            for (int j = k >> 1; j >= 1; j >>= 1) {
                float pv = __shfl_xor(v32, j);
                bool keepMin = (((l & j) == 0) == ((l & k) == 0));
                float lo = v32 < pv ? v32 : pv;
                float hi = v32 < pv ? pv : v32;
                v32 = keepMin ? lo : hi;
            }
        }
        if (l == 17) tL[rr] = v32;
    }
    __syncthreads();

    // ---- pass 2: recompute (cheap MFMA) and append j with lower = dt-sl <= T.
    float Tq[4];
#pragma unroll
    for (int q = 0; q < 4; ++q) Tq[q] = tL[grp * 4 + q];
#pragma unroll 4
    for (int t = 0; t < 32; ++t) {
        const int jb = jw + (t << 4);
        uint4 bu = *(const uint4*)(xbfU + (size_t)(jb + col) * 16 + grp * 4);
        f32x4 c0 = {0.0f, 0.0f, 0.0f, 0.0f};
        c0 = __builtin_amdgcn_mfma_f32_16x16x32_bf16(
                 afrag, __builtin_bit_cast(short8, bu), c0, 0, 0, 0);
        const float sjv = sqb[jb + col];
#pragma unroll
        for (int q = 0; q < 4; ++q) {
            float dt = __builtin_fmaf(-2.0f, c0[q], si4[q]) + sjv;
            float sl = __builtin_fmaf(si4[q] + sjv, SLC2, SLA2);
            if (dt - sl <= Tq[q]) {
                const int rr = grp * 4 + q;
                u32 s = atomicAdd(&cntL[rr], 1u);
                if (s < 64) bufL[rr][s] = ((u64)fkey(dt + sl) << 32) | (u32)(jb + col);
            }
        }
    }
    __syncthreads();

    // ---- verify + rank (v2-proven, passed absmax=0) + band-check safety net.
#pragma unroll 1
    for (int sub = 0; sub < 2; ++sub) {
        const int rr = 2 * w + sub;
        const int row = b * N_ + i0 + rr;
        const u32 cnt = cntL[rr];
        const float sqi = sqb[i0 + rr];
        bool ok = (cnt >= 18u && cnt <= 64u);   // structural guarantee when bounds valid
        u64 myc = ~0ull;
        bool band = true;
        if (ok && l < (int)cnt) {
            u64 e = bufL[rr][l];
            int jq = (int)(u32)e;
            float upv = unfkey((u32)(e >> 32));
            const float* xj = xTb + (size_t)jq * 32;    // 128 B contiguous
            float a = 0.0f;
#pragma unroll
            for (int c = 0; c < C_; ++c)
                a = __builtin_fmaf(cenL[c][rr], xj[c], a);   // exact chain, c ascending
            float d = __builtin_fmaf(-2.0f, a, sqi) + sqb[jq];
            float sl = __builtin_fmaf(sqi + sqb[jq], SLC2, SLA2);
            float eps = 0.01f + 1e-3f * fabsf(upv);
            band = (d <= upv + eps) && (d + 2.0f * sl + eps >= upv);
            myc = ((u64)fkey(d) << 32) | (u32)jq;
        }
        if (__any(!band)) ok = false;           // bounds invalid => exact fallback
        if (ok) {
            if (l < (int)cnt) bufL[rr][l] = myc;     // same-wave LDS, in-order
            u32 rank = 0;
            for (u32 m = 0; m < cnt; ++m) {
                u64 o = bufL[rr][m];                 // broadcast read
                rank += (o < myc) ? 1u : 0u;
            }
            if (l < (int)cnt && rank <= 16 && (rank & 1) == 0)
                out[row * KOUT + (rank >> 1)] = (int)((u32)myc & (N_ - 1));
            if (l < KOUT)
                out[B_ * N_ * KOUT + row * KOUT + l] = i0 + rr;
        } else {
            // exact R7 scan + pop-2 (proven) for this row
            const float sqw = sqi;
            u64 L0 = ~0ull, L1 = ~0ull, L2 = ~0ull, L3 = ~0ull, L4 = ~0ull, L5 = ~0ull;
#pragma unroll 1
            for (int m = 0; m < 64; ++m) {
                int j = l + (m << 6);
                float a = 0.0f;
#pragma unroll 1
                for (int c = 0; c < C_; ++c)
                    a = __builtin_fmaf(cenL[c][rr], xb[(size_t)c * N_ + j], a);
                float d = __builtin_fmaf(-2.0f, a, sqw) + sqb[j];
                ins6(((u64)fkey(d) << 32) | (u32)j, L0, L1, L2, L3, L4, L5);
            }
            u64 lastPop = 0;
            u32 myw = 0;
#pragma unroll 1
            for (int r = 0; r < KOUT; ++r) {
                u64 a0 = L0, a1 = L1;
#pragma unroll
                for (int off = 32; off >= 1; off >>= 1) {
                    u64 b0 = __shfl_xor(a0, off);
                    u64 b1 = __shfl_xor(a1, off);
                    u64 lo = (a0 < b0) ? a0 : b0;
                    u64 hi = (a0 < b0) ? b0 : a0;
                    u64 m1 = (a1 < b1) ? a1 : b1;
                    a0 = lo;
                    a1 = (hi < m1) ? hi : m1;
                }
                if (l == r) myw = (u32)a0;
                bool own0 = ((u32)a0 & 63) == (u32)l;
                bool own1 = ((u32)a1 & 63) == (u32)l;
                if (own0) { lastPop = a0; L0 = L1; L1 = L2; L2 = L3; L3 = L4; L4 = L5; L5 = ~0ull; }
                if (own1) { lastPop = a1; L0 = L1; L1 = L2; L2 = L3; L3 = L4; L4 = L5; L5 = ~0ull; }
                if ((own0 || own1) && L1 == ~0ull && r < KOUT - 1) {
                    L0 = L1 = L2 = L3 = L4 = L5 = ~0ull;
#pragma unroll 1
                    for (int m = 0; m < 64; ++m) {
                        int j = l + (m << 6);
                        float a = 0.0f;
#pragma unroll 1
                        for (int c = 0; c < C_; ++c)
                            a = __builtin_fmaf(cenL[c][rr], xb[(size_t)c * N_ + j], a);
                        float d = __builtin_fmaf(-2.0f, a, sqw) + sqb[j];
                        u64 kk = ((u64)fkey(d) << 32) | (u32)j;
                        if (kk > lastPop) ins6(kk, L0, L1, L2, L3, L4, L5);
                    }
                }
            }
            if (l < KOUT) {
                int o = row * KOUT + l;
                out[o] = (int)(myw & (N_ - 1));
                out[B_ * N_ * KOUT + o] = i0 + rr;
            }
        }
    }
}

extern "C" void kernel_launch(void* const* d_in, const int* in_sizes, int n_in,
                              void* d_out, int out_size, void* d_ws, size_t ws_size,
                              hipStream_t stream) {
    const float* x = (const float*)d_in[0];
    float* ws = (float*)d_ws;
    int* out = (int*)d_out;

    if (ws_size >= NEED_XT_B) {
        hipLaunchKernelGGL(prep2_kernel, dim3(B_ * N_ / 256), dim3(256), 0, stream, x, ws);
        hipLaunchKernelGGL(knn_kernel_v3, dim3(B_ * N_ / RPB2), dim3(TPB2), 0, stream,
                           x, ws, out);
    } else {
        hipLaunchKernelGGL(sq_kernel, dim3(B_ * N_ / 256), dim3(256), 0, stream, x, ws);
        hipLaunchKernelGGL(knn_kernel_old, dim3(B_ * N_ / RPB), dim3(TPB), 0, stream,
                           x, ws, out);
    }
}